// Round 1
// baseline (123.182 us; speedup 1.0000x reference)
//
#include <hip/hip_runtime.h>
#include <math.h>

#define NUM_EMB 8192
#define DIM     4
#define NTOK    32768          // B*L = 8*4096
#define NCHUNK  8
#define CHUNK   (NUM_EMB / NCHUNK)   // 1024 embeddings per chunk (16 KB as float4)
#define TPB     256

// Kernel A: per (token, chunk) partial argmax of dot(x, e) over the chunk.
// grid = (NTOK/TPB, NCHUNK); each thread owns one token, scans CHUNK embeddings
// staged in LDS. All lanes read the same LDS address per step -> broadcast.
__global__ __launch_bounds__(TPB) void vq_scan(
    const float* __restrict__ x,
    const float* __restrict__ emb,
    float* __restrict__ part_best,
    int*   __restrict__ part_idx) {

    __shared__ float4 se[CHUNK];   // 16 KB
    const int chunk = blockIdx.y;
    const int ebase = chunk * CHUNK;
    const float4* __restrict__ embv = (const float4*)emb;

    for (int i = threadIdx.x; i < CHUNK; i += TPB)
        se[i] = embv[ebase + i];
    __syncthreads();

    const int tok = blockIdx.x * TPB + threadIdx.x;
    const float4 xv = ((const float4*)x)[tok];

    float best = -INFINITY;
    int   bi   = 0;

    // 8 independent dots per iteration for ILP; sequential strict-> compares
    // preserve first-max (jnp.argmax) tie-breaking within the chunk.
    for (int n = 0; n < CHUNK; n += 8) {
        float d[8];
        #pragma unroll
        for (int j = 0; j < 8; ++j) {
            float4 e = se[n + j];
            d[j] = xv.x * e.x + xv.y * e.y + xv.z * e.z + xv.w * e.w;
        }
        #pragma unroll
        for (int j = 0; j < 8; ++j) {
            if (d[j] > best) { best = d[j]; bi = n + j; }
        }
    }

    part_best[chunk * NTOK + tok] = best;
    part_idx [chunk * NTOK + tok] = ebase + bi;
}

// Kernel B: merge per-chunk partials (ascending chunk order -> first-max
// tie-break), gather winning embedding, accumulate 2*mean(|x-e|) into out.
__global__ __launch_bounds__(TPB) void vq_reduce(
    const float* __restrict__ x,
    const float* __restrict__ emb,
    const float* __restrict__ part_best,
    const int*   __restrict__ part_idx,
    float* __restrict__ out) {

    const int tok = blockIdx.x * TPB + threadIdx.x;

    float best = -INFINITY;
    int   bi   = 0;
    #pragma unroll
    for (int c = 0; c < NCHUNK; ++c) {
        float b = part_best[c * NTOK + tok];
        int   i = part_idx [c * NTOK + tok];
        if (b > best) { best = b; bi = i; }
    }

    const float4 e  = ((const float4*)emb)[bi];
    const float4 xv = ((const float4*)x)[tok];
    float s = fabsf(xv.x - e.x) + fabsf(xv.y - e.y)
            + fabsf(xv.z - e.z) + fabsf(xv.w - e.w);

    // wave(64) shuffle reduction
    #pragma unroll
    for (int off = 32; off > 0; off >>= 1)
        s += __shfl_down(s, off, 64);

    __shared__ float ws[TPB / 64];
    if ((threadIdx.x & 63) == 0) ws[threadIdx.x >> 6] = s;
    __syncthreads();

    if (threadIdx.x == 0) {
        float t = 0.f;
        #pragma unroll
        for (int w = 0; w < TPB / 64; ++w) t += ws[w];
        // loss = (reg + embedding) = 2 * sum|x-e| / (NTOK*DIM)
        atomicAdd(out, t * (2.0f / (float)(NTOK * DIM)));
    }
}

extern "C" void kernel_launch(void* const* d_in, const int* in_sizes, int n_in,
                              void* d_out, int out_size, void* d_ws, size_t ws_size,
                              hipStream_t stream) {
    const float* x   = (const float*)d_in[0];   // [8,4096,4] fp32
    const float* emb = (const float*)d_in[1];   // [8192,4]   fp32
    float* out = (float*)d_out;                 // scalar loss

    float* part_best = (float*)d_ws;                                   // 1 MB
    int*   part_idx  = (int*)((char*)d_ws + NCHUNK * NTOK * sizeof(float)); // 1 MB

    // d_out is poisoned 0xAA before every launch; zero it for the atomics.
    hipMemsetAsync(d_out, 0, sizeof(float), stream);

    dim3 g1(NTOK / TPB, NCHUNK);
    vq_scan<<<g1, TPB, 0, stream>>>(x, emb, part_best, part_idx);
    vq_reduce<<<NTOK / TPB, TPB, 0, stream>>>(x, emb, part_best, part_idx, out);
}

// Round 2
// 109.445 us; speedup vs baseline: 1.1255x; 1.1255x over previous
//
#include <hip/hip_runtime.h>
#include <math.h>

#define NUM_EMB 8192
#define DIM     4
#define NTOK    32768                 // B*L = 8*4096
#define NCHUNK  16
#define CHUNK   (NUM_EMB / NCHUNK)    // 512 embeddings per chunk (8 KB as float4)
#define TPB     256
#define TPT     2                     // tokens per thread
#define TOKBLK  (TPB * TPT)           // 512 tokens per block
#define NTB     (NTOK / TOKBLK)       // 64 token-blocks
#define NMB     (NTOK / TPB)          // 128 merge blocks

// Kernel A: per (token, chunk) partial argmax of dot(x,e).
// grid = (NTB, NCHUNK) = 1024 blocks = 4096 waves = 4 waves/SIMD.
// Each thread owns 2 tokens; embeddings stream through LDS (uniform address
// per step -> broadcast read, 0 bank conflicts). Index tracked against a
// single VGPR counter shared by both tokens' selects.
__global__ __launch_bounds__(TPB) void vq_scan(
    const float4* __restrict__ x,
    const float4* __restrict__ emb,
    float* __restrict__ part_best,
    int*   __restrict__ part_idx) {

    __shared__ float4 se[CHUNK];   // 8 KB
    const int chunk = blockIdx.y;
    const int ebase = chunk * CHUNK;

    for (int i = threadIdx.x; i < CHUNK; i += TPB)
        se[i] = emb[ebase + i];
    __syncthreads();

    const int t0 = blockIdx.x * TOKBLK + threadIdx.x;  // coalesced
    const int t1 = t0 + TPB;                           // coalesced
    const float4 x0 = x[t0];
    const float4 x1 = x[t1];

    float best0 = -INFINITY, best1 = -INFINITY;
    int   bi0 = 0, bi1 = 0;
    int   nv = 0;   // embedding counter in a VGPR; both selects reuse it

    #pragma unroll 8
    for (int n = 0; n < CHUNK; ++n) {
        const float4 e = se[n];
        float d0 = fmaf(x0.w, e.w, fmaf(x0.z, e.z, fmaf(x0.y, e.y, x0.x * e.x)));
        float d1 = fmaf(x1.w, e.w, fmaf(x1.z, e.z, fmaf(x1.y, e.y, x1.x * e.x)));
        bool c0 = d0 > best0;           // strict > : first-max tie-break
        bool c1 = d1 > best1;
        bi0   = c0 ? nv : bi0;
        bi1   = c1 ? nv : bi1;
        best0 = c0 ? d0 : best0;
        best1 = c1 ? d1 : best1;
        ++nv;
    }

    part_best[chunk * NTOK + t0] = best0;
    part_idx [chunk * NTOK + t0] = ebase + bi0;
    part_best[chunk * NTOK + t1] = best1;
    part_idx [chunk * NTOK + t1] = ebase + bi1;
}

// Kernel B: merge 16 partials/token (ascending chunk order -> first-max
// tie-break), gather e, sum |x-e|, write one partial sum per block.
__global__ __launch_bounds__(TPB) void vq_merge(
    const float4* __restrict__ x,
    const float4* __restrict__ emb,
    const float* __restrict__ part_best,
    const int*   __restrict__ part_idx,
    float* __restrict__ blocksum) {

    const int tok = blockIdx.x * TPB + threadIdx.x;

    float best = -INFINITY;
    int   bi   = 0;
    #pragma unroll
    for (int c = 0; c < NCHUNK; ++c) {
        float b = part_best[c * NTOK + tok];
        int   i = part_idx [c * NTOK + tok];
        if (b > best) { best = b; bi = i; }
    }

    const float4 e  = emb[bi];
    const float4 xv = x[tok];
    float s = fabsf(xv.x - e.x) + fabsf(xv.y - e.y)
            + fabsf(xv.z - e.z) + fabsf(xv.w - e.w);

    #pragma unroll
    for (int off = 32; off > 0; off >>= 1)
        s += __shfl_down(s, off, 64);

    __shared__ float ws[TPB / 64];
    if ((threadIdx.x & 63) == 0) ws[threadIdx.x >> 6] = s;
    __syncthreads();

    if (threadIdx.x == 0)
        blocksum[blockIdx.x] = ws[0] + ws[1] + ws[2] + ws[3];
}

// Kernel C: one block sums the 128 block-sums and writes the loss.
// No atomics -> no memset of d_out needed.
__global__ __launch_bounds__(NMB) void vq_final(
    const float* __restrict__ blocksum,
    float* __restrict__ out) {

    float s = blocksum[threadIdx.x];   // 128 threads = 2 waves
    #pragma unroll
    for (int off = 32; off > 0; off >>= 1)
        s += __shfl_down(s, off, 64);

    __shared__ float ws[2];
    if ((threadIdx.x & 63) == 0) ws[threadIdx.x >> 6] = s;
    __syncthreads();

    if (threadIdx.x == 0)
        out[0] = (ws[0] + ws[1]) * (2.0f / (float)(NTOK * DIM));
}

extern "C" void kernel_launch(void* const* d_in, const int* in_sizes, int n_in,
                              void* d_out, int out_size, void* d_ws, size_t ws_size,
                              hipStream_t stream) {
    const float4* x   = (const float4*)d_in[0];   // [8,4096,4] fp32
    const float4* emb = (const float4*)d_in[1];   // [8192,4]   fp32
    float* out = (float*)d_out;

    // ws layout: part_best (2 MB) | part_idx (2 MB) | blocksum (512 B)
    float* part_best = (float*)d_ws;
    int*   part_idx  = (int*)  ((char*)d_ws + (size_t)NCHUNK * NTOK * sizeof(float));
    float* blocksum  = (float*)((char*)d_ws + (size_t)2 * NCHUNK * NTOK * sizeof(float));

    dim3 g1(NTB, NCHUNK);
    vq_scan <<<g1,  TPB, 0, stream>>>(x, emb, part_best, part_idx);
    vq_merge<<<NMB, TPB, 0, stream>>>(x, emb, part_best, part_idx, blocksum);
    vq_final<<<1,   NMB, 0, stream>>>(blocksum, out);
}